// Round 9
// baseline (53.517 us; speedup 1.0000x reference)
//
#include <hip/hip_runtime.h>

typedef float v4f __attribute__((ext_vector_type(4)));

namespace {
constexpr int H = 480, W = 640, B = 32;
constexpr int HW = H * W;
constexpr int W4 = W / 4;                     // 160 float4 chunks per row
constexpr int BLOCK = 256;
constexpr int NWG = B * (H / 2) * W4 / BLOCK; // 4800 (2 rows per thread)
constexpr int PER_XCD = NWG / 8;              // 600 (4800 % 8 == 0 -> bijective)
constexpr float CXf = 313.04f, CYf = 238.44f;
constexpr float RCPX = 1.0f / 582.62f;        // XLA div->mul-by-reciprocal (bit-exact, R6)
constexpr float RCPY = 1.0f / 582.69f;
}

// Exact IEEE f32 mul/add, contraction-proof (inline asm is opaque to FMA fusion).
__device__ __forceinline__ float fmul_ieee(float a, float b) {
    float r; asm("v_mul_f32 %0, %1, %2" : "=v"(r) : "v"(a), "v"(b)); return r;
}
__device__ __forceinline__ float fadd_ieee(float a, float b) {
    float r; asm("v_add_f32 %0, %1, %2" : "=v"(r) : "v"(a), "v"(b)); return r;
}
// ((A*n0) + (B*n1)) + n2 -- sequential f32, no FMA (bit-exact den/num, verified R6/R7).
__device__ __forceinline__ float abc_dot(float A, float Bv, float a0, float a1, float a2) {
    return fadd_ieee(fadd_ieee(fmul_ieee(A, a0), fmul_ieee(Bv, a1)), a2);
}
__device__ __forceinline__ float gx(int i) { return fmul_ieee((float)i - CXf, RCPX); }
__device__ __forceinline__ float gy(int i) { return fmul_ieee((float)i - CYf, RCPY); }

// Fast ratio: num * v_rcp_f32(den). Denominator stays bit-exact (that's where the
// cancellation amplification lives); ratio rel-err ~2-3 ulp -> abs out err ~0.03 << 1505.
__device__ __forceinline__ float fast_ratio(float num, float den) {
    return num * __builtin_amdgcn_rcpf(den);
}

__device__ __forceinline__ void ld4(const float* p, float* a) {
    v4f v = *reinterpret_cast<const v4f*>(p);
    a[0] = v.x; a[1] = v.y; a[2] = v.z; a[3] = v.w;
}

// Compute the 4 output channels for one row of 4 pixels.
__device__ __forceinline__ void compute_row(
    int x0, float By, float BnU, float BnD, bool okU, bool okD,
    const float nU[3][4], const float nD[3][4], const float nY[3][4],
    float nL0, float nL1, float nL2, float nR0, float nR1, float nR2,
    const float dU[4], const float dD[4], const float dY[4],
    float dm2, float dm1, float dp4, float dp5,
    v4f& vu, v4f& vd, v4f& vl, v4f& vr)
{
    float zu[4], zd[4], zl[4], zr[4];
#pragma unroll
    for (int j = 0; j < 4; ++j) {
        int x = x0 + j;
        float Ax = gx(x);
        { // z_o_up = safe_div(ABC_down, ABC_up)(y+1,x) * depth[y+2][x]
            float num = abc_dot(Ax, BnU, nU[0][j], nU[1][j], nU[2][j]);
            float den = abc_dot(Ax, By,  nU[0][j], nU[1][j], nU[2][j]);
            zu[j] = (okU && den != 0.0f) ? fast_ratio(num, den) * dU[j] : 0.0f;
        }
        { // z_o_down = safe_div(ABC_up, ABC_down)(y-1,x) * depth[y-2][x]
            float num = abc_dot(Ax, BnD, nD[0][j], nD[1][j], nD[2][j]);
            float den = abc_dot(Ax, By,  nD[0][j], nD[1][j], nD[2][j]);
            zd[j] = (okD && den != 0.0f) ? fast_ratio(num, den) * dD[j] : 0.0f;
        }
        { // z_o_left = safe_div(ABC_right, ABC_left)(y,x+1) * depth[y][x+2]
            float a0 = (j < 3) ? nY[0][j + 1] : nR0;
            float a1 = (j < 3) ? nY[1][j + 1] : nR1;
            float a2 = (j < 3) ? nY[2][j + 1] : nR2;
            float dd = (j < 2) ? dY[j + 2] : ((j == 2) ? dp4 : dp5);
            float num = abc_dot(gx(x + 2), By, a0, a1, a2);
            float den = abc_dot(Ax,        By, a0, a1, a2);
            zl[j] = ((x < W - 2) && den != 0.0f) ? fast_ratio(num, den) * dd : 0.0f;
        }
        { // z_o_right = safe_div(ABC_left, ABC_right)(y,x-1) * depth[y][x-2]
            float a0 = (j > 0) ? nY[0][j - 1] : nL0;
            float a1 = (j > 0) ? nY[1][j - 1] : nL1;
            float a2 = (j > 0) ? nY[2][j - 1] : nL2;
            float dd = (j >= 2) ? dY[j - 2] : ((j == 0) ? dm2 : dm1);
            float num = abc_dot(gx(x - 2), By, a0, a1, a2);
            float den = abc_dot(Ax,        By, a0, a1, a2);
            zr[j] = ((x >= 2) && den != 0.0f) ? fast_ratio(num, den) * dd : 0.0f;
        }
    }
    vu = v4f{ zu[0], zu[1], zu[2], zu[3] };
    vd = v4f{ zd[0], zd[1], zd[2], zd[3] };
    vl = v4f{ zl[0], zl[1], zl[2], zl[3] };
    vr = v4f{ zr[0], zr[1], zr[2], zr[3] };
}

__global__ __launch_bounds__(BLOCK) void znext_kernel(
    const float* __restrict__ depth,
    const float* __restrict__ normal,
    float* __restrict__ out)
{
    int bid = blockIdx.x;
    // XCD-chunked swizzle (bijective): XCD k owns a contiguous chunk range -> vertical
    // neighbor rows stay in the same L2; L3 retains inputs across graph replays.
    int wg = (bid & 7) * PER_XCD + (bid >> 3);
    int cid = wg * BLOCK + (int)threadIdx.x;
    constexpr int PERB = (H / 2) * W4;        // thread-tiles per batch image
    int b = cid / PERB;
    int r = cid - b * PERB;
    int yh = r / W4;
    int y0 = yh * 2;                          // even row; tile covers rows y0, y0+1
    int x0 = (r - yh * W4) * 4;

    const float* d  = depth + (size_t)b * HW;
    const float* n0 = normal + (size_t)b * 3 * HW;
    const float* n1 = n0 + HW;
    const float* n2 = n1 + HW;

    // Row offsets (clamped variants are only used where the ok-flags mask them off)
    int r0 = y0 * W;
    int r1 = (y0 + 1) * W;
    int rm1 = max(y0 - 1, 0) * W;
    int r2 = min(y0 + 2, H - 1) * W;
    int dm2r = max(y0 - 2, 0) * W;
    int dp3r = min(y0 + 3, H - 1) * W;

    // Normal rows: m1, 0, 1, 2 (4 rows x 3 channels, vectorized)
    float n_m1[3][4], n_0[3][4], n_1[3][4], n_2[3][4];
    ld4(n0 + rm1 + x0, n_m1[0]); ld4(n1 + rm1 + x0, n_m1[1]); ld4(n2 + rm1 + x0, n_m1[2]);
    ld4(n0 + r0  + x0, n_0[0]);  ld4(n1 + r0  + x0, n_0[1]);  ld4(n2 + r0  + x0, n_0[2]);
    ld4(n0 + r1  + x0, n_1[0]);  ld4(n1 + r1  + x0, n_1[1]);  ld4(n2 + r1  + x0, n_1[2]);
    ld4(n0 + r2  + x0, n_2[0]);  ld4(n1 + r2  + x0, n_2[1]);  ld4(n2 + r2  + x0, n_2[2]);

    // Depth rows: y0-2, y0-1, y0, y0+1, y0+2, y0+3
    float d_m2[4], d_m1[4], d_0[4], d_1[4], d_p2[4], d_p3[4];
    ld4(d + dm2r + x0, d_m2); ld4(d + rm1 + x0, d_m1); ld4(d + r0 + x0, d_0);
    ld4(d + r1 + x0, d_1);    ld4(d + r2 + x0, d_p2);  ld4(d + dp3r + x0, d_p3);

    // Edge scalars per row (clamped values never selected)
    int xm1 = max(x0 - 1, 0), xm2 = max(x0 - 2, 0);
    int xp4 = min(x0 + 4, W - 1), xp5 = min(x0 + 5, W - 1);
    float nL0a = n0[r0 + xm1], nL1a = n1[r0 + xm1], nL2a = n2[r0 + xm1];
    float nR0a = n0[r0 + xp4], nR1a = n1[r0 + xp4], nR2a = n2[r0 + xp4];
    float dm2a = d[r0 + xm2], dm1a = d[r0 + xm1], dp4a = d[r0 + xp4], dp5a = d[r0 + xp5];
    float nL0b = n0[r1 + xm1], nL1b = n1[r1 + xm1], nL2b = n2[r1 + xm1];
    float nR0b = n0[r1 + xp4], nR1b = n1[r1 + xp4], nR2b = n2[r1 + xp4];
    float dm2b = d[r1 + xm2], dm1b = d[r1 + xm1], dp4b = d[r1 + xp4], dp5b = d[r1 + xp5];

    // Row y0
    v4f vu0, vd0, vl0, vr0;
    compute_row(x0, gy(y0), gy(y0 + 2), gy(y0 - 2),
                (y0 < H - 2), (y0 >= 2),
                n_1, n_m1, n_0,
                nL0a, nL1a, nL2a, nR0a, nR1a, nR2a,
                d_p2, d_m2, d_0, dm2a, dm1a, dp4a, dp5a,
                vu0, vd0, vl0, vr0);
    // Row y0+1
    v4f vu1, vd1, vl1, vr1;
    compute_row(x0, gy(y0 + 1), gy(y0 + 3), gy(y0 - 1),
                (y0 + 1 < H - 2), (y0 + 1 >= 2),
                n_2, n_0, n_1,
                nL0b, nL1b, nL2b, nR0b, nR1b, nR2b,
                d_p3, d_m1, d_1, dm2b, dm1b, dp4b, dp5b,
                vu1, vd1, vl1, vr1);

    float* o = out + (size_t)b * 4 * HW + r0 + x0;
    // nontemporal: keep the 157 MB write stream out of cache -> inputs stay L3-resident
    __builtin_nontemporal_store(vu0, reinterpret_cast<v4f*>(o));
    __builtin_nontemporal_store(vd0, reinterpret_cast<v4f*>(o + HW));
    __builtin_nontemporal_store(vl0, reinterpret_cast<v4f*>(o + 2 * HW));
    __builtin_nontemporal_store(vr0, reinterpret_cast<v4f*>(o + 3 * HW));
    float* o1 = o + W;
    __builtin_nontemporal_store(vu1, reinterpret_cast<v4f*>(o1));
    __builtin_nontemporal_store(vd1, reinterpret_cast<v4f*>(o1 + HW));
    __builtin_nontemporal_store(vl1, reinterpret_cast<v4f*>(o1 + 2 * HW));
    __builtin_nontemporal_store(vr1, reinterpret_cast<v4f*>(o1 + 3 * HW));
}

extern "C" void kernel_launch(void* const* d_in, const int* in_sizes, int n_in,
                              void* d_out, int out_size, void* d_ws, size_t ws_size,
                              hipStream_t stream) {
    const float* depth  = (const float*)d_in[0];
    const float* normal = (const float*)d_in[1];
    float* out = (float*)d_out;
    znext_kernel<<<NWG, BLOCK, 0, stream>>>(depth, normal, out);
}